// Round 2
// baseline (897.159 us; speedup 1.0000x reference)
//
#include <hip/hip_runtime.h>

#define B_ 8
#define K_ 100000
#define C_ 16
#define O_ 16
#define H_ 512
#define W_ 512
#define TX 64
#define TY 8
#define GRID_OFF 256   // byte offset of f32 grid within d_ws (flag lives at offset 0)

__device__ __forceinline__ float bf_lo(unsigned int u) {
    union { unsigned int i; float f; } v; v.i = u << 16; return v.f;
}
__device__ __forceinline__ float bf_hi(unsigned int u) {
    union { unsigned int i; float f; } v; v.i = u & 0xffff0000u; return v.f;
}
__device__ __forceinline__ unsigned short f2bf(float f) {
    union { float f; unsigned int u; } v; v.f = f;
    unsigned int u = v.u;
    u += 0x7fffu + ((u >> 16) & 1u);   // round-to-nearest-even
    return (unsigned short)(u >> 16);
}

// ---------------------------------------------------------------------------
// Dtype probe: if node_xy is bf16 pairs, EVERY uint32 word decodes (low half)
// to a coordinate in [0,512]. If fp32, low halves are random mantissa bits ->
// essentially impossible for 256 words to all land in range.
// flag = 1 -> tensors are fp32 ; flag = 0 -> tensors are bf16.
// ---------------------------------------------------------------------------
__global__ void detect_fp32(const unsigned int* __restrict__ xy, int* __restrict__ flag)
{
    __shared__ int bad;
    if (threadIdx.x == 0) bad = 0;
    __syncthreads();
    unsigned int u = xy[threadIdx.x];
    float lo = bf_lo(u);
    if (!(lo >= 0.0f && lo <= 512.0f)) bad = 1;   // benign race: any writer sets 1
    __syncthreads();
    if (threadIdx.x == 0) *flag = bad;
}

// ---------------------------------------------------------------------------
// Kernel 1: project each node's features through W_{type} and scatter-add the
// 16 projected channels into a channel-last f32 grid [nb, 512, 512, 16].
// Wave-uniform branch on *flag selects bf16 vs fp32 input decoding.
// ---------------------------------------------------------------------------
__global__ __launch_bounds__(256) void scatter_proj(
    const void* __restrict__ feat, const void* __restrict__ xy,
    const int* __restrict__ types,
    const void* __restrict__ w_obj, const void* __restrict__ w_prior,
    const int* __restrict__ flag,
    float* __restrict__ grid, int b0, int nb)
{
    const int fp32 = *flag;
    __shared__ float wl[2 * O_ * C_];
    if (fp32) {
        for (int i = threadIdx.x; i < 2 * O_ * C_; i += 256)
            wl[i] = (i < O_ * C_) ? ((const float*)w_obj)[i]
                                  : ((const float*)w_prior)[i - O_ * C_];
    } else {
        for (int i = threadIdx.x; i < 2 * O_ * C_; i += 256) {
            unsigned short raw = (i < O_ * C_)
                ? ((const unsigned short*)w_obj)[i]
                : ((const unsigned short*)w_prior)[i - O_ * C_];
            union { unsigned int u; float f; } v; v.u = ((unsigned int)raw) << 16;
            wl[i] = v.f;
        }
    }
    __syncthreads();

    int n = blockIdx.x * 256 + threadIdx.x;
    if (n >= nb * K_) return;
    int lb = n / K_;
    int node = (b0 + lb) * K_ + (n - lb * K_);

    float x, y, f[16];
    if (fp32) {
        float2 p = ((const float2*)xy)[node];
        x = p.x; y = p.y;
        const float4* ff = (const float4*)feat + (size_t)node * 4;
        float4 a = ff[0], b = ff[1], c = ff[2], d = ff[3];
        f[0]=a.x; f[1]=a.y; f[2]=a.z; f[3]=a.w;
        f[4]=b.x; f[5]=b.y; f[6]=b.z; f[7]=b.w;
        f[8]=c.x; f[9]=c.y; f[10]=c.z; f[11]=c.w;
        f[12]=d.x; f[13]=d.y; f[14]=d.z; f[15]=d.w;
    } else {
        unsigned int uxy = ((const unsigned int*)xy)[node];
        x = bf_lo(uxy); y = bf_hi(uxy);
        const uint4* ff = (const uint4*)feat + (size_t)node * 2;
        uint4 A = ff[0], Bv = ff[1];
        f[0]=bf_lo(A.x);  f[1]=bf_hi(A.x);  f[2]=bf_lo(A.y);  f[3]=bf_hi(A.y);
        f[4]=bf_lo(A.z);  f[5]=bf_hi(A.z);  f[6]=bf_lo(A.w);  f[7]=bf_hi(A.w);
        f[8]=bf_lo(Bv.x); f[9]=bf_hi(Bv.x); f[10]=bf_lo(Bv.y); f[11]=bf_hi(Bv.y);
        f[12]=bf_lo(Bv.z); f[13]=bf_hi(Bv.z); f[14]=bf_lo(Bv.w); f[15]=bf_hi(Bv.w);
    }

    int xs = min(max((int)rintf(x), 0), W_ - 1);  // rintf == round-half-even == jnp.round
    int ys = min(max((int)rintf(y), 0), H_ - 1);
    const float* wrow = &wl[(types[node] != 0) ? O_ * C_ : 0];

    float* gb = grid + (((size_t)lb * H_ + ys) * W_ + xs) * O_;
    #pragma unroll
    for (int o = 0; o < O_; ++o) {
        float acc = 0.f;
        #pragma unroll
        for (int c = 0; c < C_; ++c) acc = fmaf(wrow[o * C_ + c], f[c], acc);
        atomicAdd(gb + o, acc);   // 16 contiguous f32 atomics -> ~1 L2 line/node
    }
}

// ---------------------------------------------------------------------------
// Kernel 2: 3x3 depthwise conv (SAME, zero pad) on channel-last f32 grid,
// writing output in [B,16,512,512] as bf16 or fp32 per *flag.
// Tile 64x8 px, all 16 ch in LDS; lane map q=tid&3 -> conflict-free b128 LDS.
// Row symmetry [a,b,a]: per input row compute hA (edge) / hB (center) once.
// ---------------------------------------------------------------------------
__global__ __launch_bounds__(256) void conv_splat(
    const float4* __restrict__ grid, void* __restrict__ out,
    const int* __restrict__ flag, int b0)
{
    __shared__ float4 lds[(TX + 2) * (TY + 2) * 4];
    const int lb = blockIdx.z;
    const int bx = blockIdx.x, by = blockIdx.y;

    for (int i = threadIdx.x; i < (TX + 2) * (TY + 2) * 4; i += 256) {
        int q = i & 3, p = i >> 2;
        int lx = p % (TX + 2), ly = p / (TX + 2);
        int gx = bx * TX - 1 + lx, gy = by * TY - 1 + ly;
        float4 v = make_float4(0.f, 0.f, 0.f, 0.f);
        if (gx >= 0 && gx < W_ && gy >= 0 && gy < H_)
            v = grid[(((size_t)lb * H_ + gy) * W_ + gx) * 4 + q];
        lds[i] = v;
    }
    __syncthreads();

    const int q = threadIdx.x & 3, px = threadIdx.x >> 2;
    float4 acc[TY];
    #pragma unroll
    for (int r = 0; r < TY; ++r) acc[r] = make_float4(0.f, 0.f, 0.f, 0.f);

    #pragma unroll
    for (int iy = 0; iy < TY + 2; ++iy) {
        const float4* row = &lds[(iy * (TX + 2) + px) * 4 + q];
        float4 vL = row[0], vC = row[4], vR = row[8];
        float4 hA, hB;
        float sx = vL.x + vR.x, sy = vL.y + vR.y, sz = vL.z + vR.z, sw = vL.w + vR.w;
        hA.x = fmaf(0.075f, sx, 0.125f * vC.x);
        hA.y = fmaf(0.075f, sy, 0.125f * vC.y);
        hA.z = fmaf(0.075f, sz, 0.125f * vC.z);
        hA.w = fmaf(0.075f, sw, 0.125f * vC.w);
        hB.x = fmaf(0.125f, sx, 0.3f * vC.x);
        hB.y = fmaf(0.125f, sy, 0.3f * vC.y);
        hB.z = fmaf(0.125f, sz, 0.3f * vC.z);
        hB.w = fmaf(0.125f, sw, 0.3f * vC.w);
        if (iy <= TY - 1) {            // input row is top neighbor of out row iy
            acc[iy].x += hA.x; acc[iy].y += hA.y; acc[iy].z += hA.z; acc[iy].w += hA.w;
        }
        if (iy >= 1 && iy <= TY) {     // center tap of out row iy-1
            acc[iy-1].x += hB.x; acc[iy-1].y += hB.y; acc[iy-1].z += hB.z; acc[iy-1].w += hB.w;
        }
        if (iy >= 2) {                 // bottom neighbor of out row iy-2
            acc[iy-2].x += hA.x; acc[iy-2].y += hA.y; acc[iy-2].z += hA.z; acc[iy-2].w += hA.w;
        }
    }

    const int fp32 = *flag;
    const int b = b0 + lb;
    const int xg = bx * TX + px;
    if (fp32) {
        float* o32 = (float*)out;
        #pragma unroll
        for (int r = 0; r < TY; ++r) {
            int yg = by * TY + r;
            size_t base = (((size_t)b * O_) * H_ + yg) * W_ + xg;
            o32[base + (size_t)(q * 4 + 0) * H_ * W_] = acc[r].x;
            o32[base + (size_t)(q * 4 + 1) * H_ * W_] = acc[r].y;
            o32[base + (size_t)(q * 4 + 2) * H_ * W_] = acc[r].z;
            o32[base + (size_t)(q * 4 + 3) * H_ * W_] = acc[r].w;
        }
    } else {
        unsigned short* o16 = (unsigned short*)out;
        #pragma unroll
        for (int r = 0; r < TY; ++r) {
            int yg = by * TY + r;
            size_t base = (((size_t)b * O_) * H_ + yg) * W_ + xg;
            o16[base + (size_t)(q * 4 + 0) * H_ * W_] = f2bf(acc[r].x);
            o16[base + (size_t)(q * 4 + 1) * H_ * W_] = f2bf(acc[r].y);
            o16[base + (size_t)(q * 4 + 2) * H_ * W_] = f2bf(acc[r].z);
            o16[base + (size_t)(q * 4 + 3) * H_ * W_] = f2bf(acc[r].w);
        }
    }
}

extern "C" void kernel_launch(void* const* d_in, const int* in_sizes, int n_in,
                              void* d_out, int out_size, void* d_ws, size_t ws_size,
                              hipStream_t stream)
{
    const void* feat = d_in[0];                    // [8,100000,16] bf16 or fp32
    const void* xy = d_in[1];                      // [8,100000,2]  bf16 or fp32
    // d_in[2] = hw (int64 [2]) -- constants 512x512, unused
    const int* types = (const int*)d_in[3];        // int32 [8,100000]
    const void* w_obj = d_in[4];                   // [16,16]
    const void* w_prior = d_in[5];                 // [16,16]

    int* flag = (int*)d_ws;
    float* grid_base = (float*)((char*)d_ws + GRID_OFF);

    detect_fp32<<<1, 256, 0, stream>>>((const unsigned int*)xy, flag);

    const size_t per_b = (size_t)H_ * W_ * O_ * sizeof(float);  // 16 MiB per batch
    size_t avail = (ws_size > GRID_OFF) ? ws_size - GRID_OFF : 0;
    int nb_chunk = (int)(avail / per_b);
    if (nb_chunk > B_) nb_chunk = B_;
    if (nb_chunk < 1) nb_chunk = 1;   // (requires ws_size >= 16 MiB + 256 B)

    for (int b0 = 0; b0 < B_; b0 += nb_chunk) {
        int nb = (B_ - b0 < nb_chunk) ? (B_ - b0) : nb_chunk;
        hipMemsetAsync(grid_base, 0, per_b * (size_t)nb, stream);
        int nblocks = (nb * K_ + 255) / 256;
        scatter_proj<<<nblocks, 256, 0, stream>>>(feat, xy, types, w_obj, w_prior,
                                                  flag, grid_base, b0, nb);
        conv_splat<<<dim3(W_ / TX, H_ / TY, nb), 256, 0, stream>>>(
            (const float4*)grid_base, d_out, flag, b0);
    }
}

// Round 3
// 342.107 us; speedup vs baseline: 2.6225x; 2.6225x over previous
//
#include <hip/hip_runtime.h>

#define B_ 8
#define K_ 100000
#define NODES (B_ * K_)
#define C_ 16
#define O_ 16
#define H_ 512
#define W_ 512
#define TSX 32
#define TSY 16
#define NTX (W_ / TSX)          // 16 tile cols
#define NTY (H_ / TSY)          // 32 tile rows
#define NBKT (B_ * NTX * NTY)   // 4096 buckets
#define CAP 512                 // slots per bucket (lambda=233, >18 sigma margin)
#define EX (TSX + 2)            // 34 expanded width (1px halo)
#define EY (TSY + 2)            // 18 expanded height
#define PLANE (EX * EY)         // 612 floats per channel plane
#define FILL_BLOCKS 64
#define CHUNK (NODES / FILL_BLOCKS)  // 12500
// ws layout: [0] flag int | [256] cursor[4096] int | [32768] ids[4096*512] int (8 MiB)
#define CUR_OFF 256
#define IDS_OFF 32768

__device__ __forceinline__ float bf_lo(unsigned int u) {
    union { unsigned int i; float f; } v; v.i = u << 16; return v.f;
}
__device__ __forceinline__ float bf_hi(unsigned int u) {
    union { unsigned int i; float f; } v; v.i = u & 0xffff0000u; return v.f;
}
__device__ __forceinline__ unsigned short f2bf(float f) {
    union { float f; unsigned int u; } v; v.f = f;
    unsigned int u = v.u;
    u += 0x7fffu + ((u >> 16) & 1u);   // round-to-nearest-even
    return (unsigned short)(u >> 16);
}

// ---------------------------------------------------------------------------
// Dtype probe (kept from R2 — it passed): bf16 xy pairs always decode in
// [0,512]; fp32 low halves are random mantissa bits. flag=1 -> fp32.
// ---------------------------------------------------------------------------
__global__ void detect_fp32(const unsigned int* __restrict__ xy, int* __restrict__ flag)
{
    __shared__ int bad;
    if (threadIdx.x == 0) bad = 0;
    __syncthreads();
    unsigned int u = xy[threadIdx.x];
    float lo = bf_lo(u);
    if (!(lo >= 0.0f && lo <= 512.0f)) bad = 1;
    __syncthreads();
    if (threadIdx.x == 0) *flag = bad;
}

__device__ __forceinline__ void decode_xy(const void* xy, int fp32, int n,
                                          int& xs, int& ys)
{
    float x, y;
    if (fp32) { float2 p = ((const float2*)xy)[n]; x = p.x; y = p.y; }
    else { unsigned int u = ((const unsigned int*)xy)[n]; x = bf_lo(u); y = bf_hi(u); }
    xs = min(max((int)rintf(x), 0), W_ - 1);   // rintf == round-half-even == jnp.round
    ys = min(max((int)rintf(y), 0), H_ - 1);
}

// ---------------------------------------------------------------------------
// Pass 1: bin nodes into expanded-tile buckets. LDS histogram + one global
// chunk-reservation atomic per (block, nonzero bucket): ~250k global atomics
// total (vs 12.8M in the R2 scatter). Node on a tile boundary lands in up to
// 4 buckets (halo duplication ~1.2x).
// ---------------------------------------------------------------------------
__global__ __launch_bounds__(256) void fill_bins(
    const void* __restrict__ xy, const int* __restrict__ flag,
    int* __restrict__ cursor, int* __restrict__ ids)
{
    __shared__ int hist[NBKT];
    const int fp32 = *flag;
    for (int j = threadIdx.x; j < NBKT; j += 256) hist[j] = 0;
    __syncthreads();

    const int s = blockIdx.x * CHUNK, e = s + CHUNK;

    for (int i = s + threadIdx.x; i < e; i += 256) {
        int xs, ys; decode_xy(xy, fp32, i, xs, ys);
        int bb = i / K_;
        int xlo = max((xs - 1) >> 5, 0), xhi = min((xs + 1) >> 5, NTX - 1);
        int ylo = max((ys - 1) >> 4, 0), yhi = min((ys + 1) >> 4, NTY - 1);
        for (int tyy = ylo; tyy <= yhi; ++tyy)
            for (int txx = xlo; txx <= xhi; ++txx)
                atomicAdd(&hist[(bb * NTY + tyy) * NTX + txx], 1);
    }
    __syncthreads();

    for (int j = threadIdx.x; j < NBKT; j += 256) {
        int c = hist[j];
        hist[j] = c ? atomicAdd(&cursor[j], c) : 0;   // reserve contiguous chunk
    }
    __syncthreads();

    for (int i = s + threadIdx.x; i < e; i += 256) {
        int xs, ys; decode_xy(xy, fp32, i, xs, ys);
        int bb = i / K_;
        int xlo = max((xs - 1) >> 5, 0), xhi = min((xs + 1) >> 5, NTX - 1);
        int ylo = max((ys - 1) >> 4, 0), yhi = min((ys + 1) >> 4, NTY - 1);
        for (int tyy = ylo; tyy <= yhi; ++tyy)
            for (int txx = xlo; txx <= xhi; ++txx) {
                int bk = (bb * NTY + tyy) * NTX + txx;
                int slot = atomicAdd(&hist[bk], 1);   // LDS: base + local idx
                if (slot < CAP) ids[bk * CAP + slot] = i;
            }
    }
}

// ---------------------------------------------------------------------------
// Pass 2 (fused): per 32x16 tile — gather bucket nodes, project through
// W_{type}, accumulate raster into LDS (f32 atomics, planar stride 612 ->
// random banks), then 3x3 depthwise conv in-LDS and direct output store.
// No global intermediate grid at all.
// ---------------------------------------------------------------------------
__global__ __launch_bounds__(512) void tile_fused(
    const void* __restrict__ feat, const void* __restrict__ xy,
    const int* __restrict__ types,
    const void* __restrict__ w_obj, const void* __restrict__ w_prior,
    const int* __restrict__ flag,
    const int* __restrict__ cursor, const int* __restrict__ ids,
    void* __restrict__ out)
{
    __shared__ float accs[O_ * PLANE];   // 9792 f32 = 39.2 KB
    __shared__ float wl[2 * O_ * C_];    // 2 KB
    const int fp32 = *flag;

    const int tx = blockIdx.x, ty = blockIdx.y, b = blockIdx.z;
    const int x0 = tx * TSX, y0 = ty * TSY;
    const int bucket = (b * NTY + ty) * NTX + tx;

    for (int i = threadIdx.x; i < O_ * PLANE; i += 512) accs[i] = 0.f;
    if (fp32) {
        for (int i = threadIdx.x; i < 2 * O_ * C_; i += 512)
            wl[i] = (i < O_ * C_) ? ((const float*)w_obj)[i]
                                  : ((const float*)w_prior)[i - O_ * C_];
    } else {
        for (int i = threadIdx.x; i < 2 * O_ * C_; i += 512) {
            unsigned short raw = (i < O_ * C_)
                ? ((const unsigned short*)w_obj)[i]
                : ((const unsigned short*)w_prior)[i - O_ * C_];
            union { unsigned int u; float f; } v; v.u = ((unsigned int)raw) << 16;
            wl[i] = v.f;
        }
    }
    __syncthreads();

    int cnt = cursor[bucket];
    if (cnt > CAP) cnt = CAP;

    for (int i = threadIdx.x; i < cnt; i += 512) {
        int n = ids[bucket * CAP + i];
        int xs, ys; decode_xy(xy, fp32, n, xs, ys);
        int lx = xs - x0 + 1, ly = ys - y0 + 1;   // in [0,33] x [0,17] by binning

        float f[16];
        if (fp32) {
            const float4* ff = (const float4*)feat + (size_t)n * 4;
            float4 a = ff[0], bb = ff[1], c = ff[2], d = ff[3];
            f[0]=a.x; f[1]=a.y; f[2]=a.z; f[3]=a.w;
            f[4]=bb.x; f[5]=bb.y; f[6]=bb.z; f[7]=bb.w;
            f[8]=c.x; f[9]=c.y; f[10]=c.z; f[11]=c.w;
            f[12]=d.x; f[13]=d.y; f[14]=d.z; f[15]=d.w;
        } else {
            const uint4* ff = (const uint4*)feat + (size_t)n * 2;
            uint4 A = ff[0], Bv = ff[1];
            f[0]=bf_lo(A.x);  f[1]=bf_hi(A.x);  f[2]=bf_lo(A.y);  f[3]=bf_hi(A.y);
            f[4]=bf_lo(A.z);  f[5]=bf_hi(A.z);  f[6]=bf_lo(A.w);  f[7]=bf_hi(A.w);
            f[8]=bf_lo(Bv.x); f[9]=bf_hi(Bv.x); f[10]=bf_lo(Bv.y); f[11]=bf_hi(Bv.y);
            f[12]=bf_lo(Bv.z); f[13]=bf_hi(Bv.z); f[14]=bf_lo(Bv.w); f[15]=bf_hi(Bv.w);
        }

        const float* wrow = &wl[(types[n] != 0) ? O_ * C_ : 0];
        float* cell = &accs[ly * EX + lx];
        #pragma unroll
        for (int o = 0; o < O_; ++o) {
            float acc = 0.f;
            #pragma unroll
            for (int c = 0; c < C_; ++c) acc = fmaf(wrow[o * C_ + c], f[c], acc);
            atomicAdd(cell + o * PLANE, acc);   // LDS atomic, random-bank spread
        }
    }
    __syncthreads();

    // conv: thread = (o = tid>>5, x = tid&31); rolling vertical window.
    const int x = threadIdx.x & 31;
    const int o = threadIdx.x >> 5;
    const float* pl = &accs[o * PLANE + x];
    float hA2 = 0.f, hA1 = 0.f, hB1 = 0.f;
    const size_t obase = (((size_t)(b * O_ + o)) * H_) * W_;

    #pragma unroll
    for (int iy = 0; iy < EY; ++iy) {
        float l = pl[iy * EX], c = pl[iy * EX + 1], r = pl[iy * EX + 2];
        float sfx = l + r;
        float hA = fmaf(0.075f, sfx, 0.125f * c);
        float hB = fmaf(0.125f, sfx, 0.3f * c);
        if (iy >= 2) {
            float v = hA2 + hB1 + hA;
            size_t oi = obase + (size_t)(y0 + iy - 2) * W_ + (x0 + x);
            if (fp32) ((float*)out)[oi] = v;
            else      ((unsigned short*)out)[oi] = f2bf(v);
        }
        hA2 = hA1; hA1 = hA; hB1 = hB;
    }
}

extern "C" void kernel_launch(void* const* d_in, const int* in_sizes, int n_in,
                              void* d_out, int out_size, void* d_ws, size_t ws_size,
                              hipStream_t stream)
{
    const void* feat = d_in[0];                    // [8,100000,16] fp32 (or bf16)
    const void* xy = d_in[1];                      // [8,100000,2]
    // d_in[2] = hw (int64 [2]) -- constants 512x512, unused
    const int* types = (const int*)d_in[3];        // int32 [8,100000]
    const void* w_obj = d_in[4];                   // [16,16]
    const void* w_prior = d_in[5];                 // [16,16]

    int* flag = (int*)d_ws;
    int* cursor = (int*)((char*)d_ws + CUR_OFF);
    int* ids = (int*)((char*)d_ws + IDS_OFF);

    detect_fp32<<<1, 256, 0, stream>>>((const unsigned int*)xy, flag);
    hipMemsetAsync(cursor, 0, NBKT * sizeof(int), stream);
    fill_bins<<<FILL_BLOCKS, 256, 0, stream>>>(xy, flag, cursor, ids);
    tile_fused<<<dim3(NTX, NTY, B_), 512, 0, stream>>>(
        feat, xy, types, w_obj, w_prior, flag, cursor, ids, d_out);
}

// Round 4
// 287.082 us; speedup vs baseline: 3.1251x; 1.1917x over previous
//
#include <hip/hip_runtime.h>

#define B_ 8
#define K_ 100000
#define NODES (B_ * K_)
#define C_ 16
#define O_ 16
#define H_ 512
#define W_ 512
#define TSX 32
#define TSY 16
#define NTX (W_ / TSX)          // 16 tile cols
#define NTY (H_ / TSY)          // 32 tile rows
#define NBKT (B_ * NTX * NTY)   // 4096 buckets
#define CAP 512                 // slots/bucket (lambda≈233 incl. halo, >18 sigma)
#define EX (TSX + 2)            // 34
#define EY (TSY + 2)            // 18
#define PLANE (EX * EY)         // 612
#define FB 256                  // fill_bins blocks (32 per batch)
#define FCHUNK (K_ / (FB / B_)) // 3125 nodes per fill block (single batch)
// ws layout: [0..16KB) cursor[4096] | [16KB..) ids[4096*512] int (8 MiB)
#define IDS_OFF 16384

__device__ __forceinline__ float bf_lo(unsigned int u) {
    union { unsigned int i; float f; } v; v.i = u << 16; return v.f;
}
__device__ __forceinline__ float bf_hi(unsigned int u) {
    union { unsigned int i; float f; } v; v.i = u & 0xffff0000u; return v.f;
}
__device__ __forceinline__ unsigned short f2bf(float f) {
    union { float f; unsigned int u; } v; v.f = f;
    unsigned int u = v.u;
    u += 0x7fffu + ((u >> 16) & 1u);   // round-to-nearest-even
    return (unsigned short)(u >> 16);
}

// Inline dtype probe: bf16 xy pairs always decode (low half) into [0,512];
// fp32 low halves are random mantissa bits -> P(all 256 pass)≈1e-146.
// Each block computes it locally (1 KB coalesced read, L2-hot): no extra
// dispatch, no cross-kernel dependency. bad!=0 -> tensors are fp32.
__device__ __forceinline__ void probe_fp32(const unsigned int* xy, int tid,
                                           int* bad /*LDS*/)
{
    if (tid == 0) *bad = 0;
    // caller must __syncthreads() before AND after; we fold into existing syncs
    if (tid < 256) {
        float lo = bf_lo(xy[tid]);
        if (!(lo >= 0.0f && lo <= 512.0f)) *bad = 1;
    }
}

__device__ __forceinline__ void decode_xy(const void* xy, int fp32, int n,
                                          int& xs, int& ys)
{
    float x, y;
    if (fp32) { float2 p = ((const float2*)xy)[n]; x = p.x; y = p.y; }
    else { unsigned int u = ((const unsigned int*)xy)[n]; x = bf_lo(u); y = bf_hi(u); }
    xs = min(max((int)rintf(x), 0), W_ - 1);   // rintf == round-half-even == jnp.round
    ys = min(max((int)rintf(y), 0), H_ - 1);
}

// ---------------------------------------------------------------------------
// Pass 1: bin nodes. 256 blocks, each a 3125-node chunk of ONE batch ->
// 512-entry LDS histogram; xy decoded once (cached in LDS rec[]); types read
// coalesced. Emits fully-packed records: local_id|type|lx|ly so tile_fused
// needs zero per-node gathers besides feat.
// ---------------------------------------------------------------------------
__global__ __launch_bounds__(256) void fill_bins(
    const void* __restrict__ xy, const int* __restrict__ types,
    int* __restrict__ cursor, int* __restrict__ ids)
{
    __shared__ int hist[NTX * NTY];          // 512
    __shared__ unsigned int rec[FCHUNK];     // 3125 packed xs|ys|type
    __shared__ int bad;

    const int tid = threadIdx.x;
    probe_fp32((const unsigned int*)xy, tid, &bad);
    for (int j = tid; j < NTX * NTY; j += 256) hist[j] = 0;
    __syncthreads();
    const int fp32 = bad;

    const int bb = blockIdx.x >> 5;                    // 32 blocks per batch
    const int local0 = (blockIdx.x & 31) * FCHUNK;     // node offset within batch
    const int s = bb * K_ + local0;

    for (int ii = tid; ii < FCHUNK; ii += 256) {
        int n = s + ii;
        int xs, ys; decode_xy(xy, fp32, n, xs, ys);
        int t = (types[n] != 0);
        rec[ii] = (unsigned)(xs | (ys << 9) | (t << 18));
        int xlo = max((xs - 1) >> 5, 0), xhi = min((xs + 1) >> 5, NTX - 1);
        int ylo = max((ys - 1) >> 4, 0), yhi = min((ys + 1) >> 4, NTY - 1);
        for (int tyy = ylo; tyy <= yhi; ++tyy)
            for (int txx = xlo; txx <= xhi; ++txx)
                atomicAdd(&hist[tyy * NTX + txx], 1);
    }
    __syncthreads();

    for (int j = tid; j < NTX * NTY; j += 256) {
        int c = hist[j];
        hist[j] = c ? atomicAdd(&cursor[bb * NTX * NTY + j], c) : 0;  // reserve
    }
    __syncthreads();

    for (int ii = tid; ii < FCHUNK; ii += 256) {
        unsigned r = rec[ii];
        int xs = r & 511, ys = (r >> 9) & 511, t = (r >> 18) & 1;
        int local = local0 + ii;                       // 17 bits (<100000)
        int xlo = max((xs - 1) >> 5, 0), xhi = min((xs + 1) >> 5, NTX - 1);
        int ylo = max((ys - 1) >> 4, 0), yhi = min((ys + 1) >> 4, NTY - 1);
        for (int tyy = ylo; tyy <= yhi; ++tyy)
            for (int txx = xlo; txx <= xhi; ++txx) {
                int bk = tyy * NTX + txx;
                int slot = atomicAdd(&hist[bk], 1);    // base + local index
                if (slot < CAP) {
                    int lx = xs - (txx << 5) + 1;      // [0,33] 6 bits
                    int ly = ys - (tyy << 4) + 1;      // [0,17] 5 bits
                    ids[(bb * NTX * NTY + bk) * CAP + slot] =
                        local | (t << 17) | (lx << 18) | (ly << 24);
                }
            }
    }
}

// ---------------------------------------------------------------------------
// Pass 2 (fused): per 32x16 tile — read packed records (coalesced), ONE
// dependent load (feat), project through W_{type}, accumulate raster in LDS
// (f32 atomics), 3x3 depthwise conv in-LDS, non-temporal direct store.
// ---------------------------------------------------------------------------
__global__ __launch_bounds__(512) void tile_fused(
    const void* __restrict__ feat, const void* __restrict__ xy,
    const void* __restrict__ w_obj, const void* __restrict__ w_prior,
    const int* __restrict__ cursor, const int* __restrict__ ids,
    void* __restrict__ out)
{
    __shared__ float accs[O_ * PLANE];   // 39.2 KB
    __shared__ float wl[2 * O_ * C_];    // 2 KB
    __shared__ int bad;

    const int tid = threadIdx.x;
    const int tx = blockIdx.x, ty = blockIdx.y, b = blockIdx.z;
    const int bucket = (b * NTY + ty) * NTX + tx;
    int cnt = cursor[bucket];            // issue early, consumed after sync
    if (cnt > CAP) cnt = CAP;

    probe_fp32((const unsigned int*)xy, tid, &bad);
    for (int i = tid; i < O_ * PLANE; i += 512) accs[i] = 0.f;
    __syncthreads();
    const int fp32 = bad;

    if (fp32) {
        for (int i = tid; i < 2 * O_ * C_; i += 512)
            wl[i] = (i < O_ * C_) ? ((const float*)w_obj)[i]
                                  : ((const float*)w_prior)[i - O_ * C_];
    } else {
        for (int i = tid; i < 2 * O_ * C_; i += 512) {
            unsigned short raw = (i < O_ * C_)
                ? ((const unsigned short*)w_obj)[i]
                : ((const unsigned short*)w_prior)[i - O_ * C_];
            union { unsigned int u; float f; } v; v.u = ((unsigned int)raw) << 16;
            wl[i] = v.f;
        }
    }
    __syncthreads();

    for (int i = tid; i < cnt; i += 512) {
        unsigned p = (unsigned)ids[bucket * CAP + i];
        int local = p & 0x1FFFF;
        int t  = (p >> 17) & 1;
        int lx = (p >> 18) & 63;
        int ly = (p >> 24) & 31;
        size_t n = (size_t)b * K_ + local;

        float f[16];
        if (fp32) {
            const float4* ff = (const float4*)feat + n * 4;
            float4 a = ff[0], bb2 = ff[1], c = ff[2], d = ff[3];
            f[0]=a.x; f[1]=a.y; f[2]=a.z; f[3]=a.w;
            f[4]=bb2.x; f[5]=bb2.y; f[6]=bb2.z; f[7]=bb2.w;
            f[8]=c.x; f[9]=c.y; f[10]=c.z; f[11]=c.w;
            f[12]=d.x; f[13]=d.y; f[14]=d.z; f[15]=d.w;
        } else {
            const uint4* ff = (const uint4*)feat + n * 2;
            uint4 A = ff[0], Bv = ff[1];
            f[0]=bf_lo(A.x);  f[1]=bf_hi(A.x);  f[2]=bf_lo(A.y);  f[3]=bf_hi(A.y);
            f[4]=bf_lo(A.z);  f[5]=bf_hi(A.z);  f[6]=bf_lo(A.w);  f[7]=bf_hi(A.w);
            f[8]=bf_lo(Bv.x); f[9]=bf_hi(Bv.x); f[10]=bf_lo(Bv.y); f[11]=bf_hi(Bv.y);
            f[12]=bf_lo(Bv.z); f[13]=bf_hi(Bv.z); f[14]=bf_lo(Bv.w); f[15]=bf_hi(Bv.w);
        }

        const float* wrow = &wl[t * O_ * C_];
        float* cell = &accs[ly * EX + lx];
        #pragma unroll
        for (int o = 0; o < O_; ++o) {
            float acc = 0.f;
            #pragma unroll
            for (int c = 0; c < C_; ++c) acc = fmaf(wrow[o * C_ + c], f[c], acc);
            atomicAdd(cell + o * PLANE, acc);
        }
    }
    __syncthreads();

    // conv: thread = (o = tid>>5, x = tid&31); rolling vertical window.
    const int x = tid & 31;
    const int o = tid >> 5;
    const float* pl = &accs[o * PLANE + x];
    float hA2 = 0.f, hA1 = 0.f, hB1 = 0.f;
    const int x0 = tx * TSX, y0 = ty * TSY;
    const size_t obase = (((size_t)(b * O_ + o)) * H_) * W_;

    #pragma unroll
    for (int iy = 0; iy < EY; ++iy) {
        float l = pl[iy * EX], c = pl[iy * EX + 1], r = pl[iy * EX + 2];
        float sfx = l + r;
        float hA = fmaf(0.075f, sfx, 0.125f * c);
        float hB = fmaf(0.125f, sfx, 0.3f * c);
        if (iy >= 2) {
            float v = hA2 + hB1 + hA;
            size_t oi = obase + (size_t)(y0 + iy - 2) * W_ + (x0 + x);
            if (fp32) __builtin_nontemporal_store(v, (float*)out + oi);
            else      __builtin_nontemporal_store(f2bf(v), (unsigned short*)out + oi);
        }
        hA2 = hA1; hA1 = hA; hB1 = hB;
    }
}

extern "C" void kernel_launch(void* const* d_in, const int* in_sizes, int n_in,
                              void* d_out, int out_size, void* d_ws, size_t ws_size,
                              hipStream_t stream)
{
    const void* feat = d_in[0];                    // [8,100000,16] fp32 (or bf16)
    const void* xy = d_in[1];                      // [8,100000,2]
    // d_in[2] = hw (int64 [2]) -- constants 512x512, unused
    const int* types = (const int*)d_in[3];        // int32 [8,100000]
    const void* w_obj = d_in[4];                   // [16,16]
    const void* w_prior = d_in[5];                 // [16,16]

    int* cursor = (int*)d_ws;
    int* ids = (int*)((char*)d_ws + IDS_OFF);

    hipMemsetAsync(cursor, 0, NBKT * sizeof(int), stream);
    fill_bins<<<FB, 256, 0, stream>>>(xy, types, cursor, ids);
    tile_fused<<<dim3(NTX, NTY, B_), 512, 0, stream>>>(
        feat, xy, w_obj, w_prior, cursor, ids, d_out);
}